// Round 1
// baseline (460.246 us; speedup 1.0000x reference)
//
#include <hip/hip_runtime.h>
#include <math.h>

// Fused fab_penalty_ls_curve: 13-point stencil over eps + global reduction.
// ref: phi_x,phi_y = gradient(eps); +1e-12; phi_xx,phi_xy = gradient(phi_x);
//      phi_yy = gradient(phi_y, axis=1);
//      k = (ex^2*eyy - 2 ex ey exy + ey^2 exx)/eps_v^3
//      cc = |k * atan(eps_v/(eps+1e-6))| - pi/1.1
//      out = nansum(max(cc,0) * d^2)

constexpr int TX = 128;   // output tile cols per block
constexpr int TY = 32;    // output tile rows per block
constexpr int HW = TX + 4;  // 132 (halo 2 each side)
constexpr int HH = TY + 4;  // 36

__global__ __launch_bounds__(256)
void fab_penalty_kernel(const float* __restrict__ eps,
                        const float* __restrict__ gs,
                        float* __restrict__ out, int n) {
    __shared__ float s[HH][HW];
    __shared__ float wsum[4];

    const float d      = *gs;
    const float inv_d  = 1.0f / d;
    const float inv_2d = 0.5f / d;

    const int tx = threadIdx.x;           // 0..63
    const int ty = threadIdx.y;           // 0..3
    const int gx0 = blockIdx.x * TX;
    const int gy0 = blockIdx.y * TY;

    // ---- load halo tile (clamped indices at borders; clamped values are
    //      never consumed by the edge formulas, clamping only avoids OOB) ----
    for (int r = ty; r < HH; r += 4) {
        int gi = gy0 - 2 + r;
        gi = min(max(gi, 0), n - 1);
        const float* row = eps + (size_t)gi * (size_t)n;
        for (int c = tx; c < HW; c += 64) {
            int gj = gx0 - 2 + c;
            gj = min(max(gj, 0), n - 1);
            s[r][c] = row[gj];
        }
    }
    __syncthreads();

    // numpy.gradient edge_order=1 along rows (axis 0), value of phi_x at
    // tile-local (r,c) with global row index i.  Includes the +SC term.
    auto EXAT = [&](int r, int c, int i) -> float {
        float v;
        if (i == 0)          v = (s[r + 1][c] - s[r][c]) * inv_d;
        else if (i == n - 1) v = (s[r][c] - s[r - 1][c]) * inv_d;
        else                 v = (s[r + 1][c] - s[r - 1][c]) * inv_2d;
        return v + 1e-12f;
    };
    // along cols (axis 1), value of phi_y at (r,c), global col j.
    auto EYAT = [&](int r, int c, int j) -> float {
        float v;
        if (j == 0)          v = (s[r][c + 1] - s[r][c]) * inv_d;
        else if (j == n - 1) v = (s[r][c] - s[r][c - 1]) * inv_d;
        else                 v = (s[r][c + 1] - s[r][c - 1]) * inv_2d;
        return v + 1e-12f;
    };

    float acc = 0.0f;

    #pragma unroll
    for (int k = 0; k < TY / 4; ++k) {
        const int li = ty + 4 * k;
        #pragma unroll
        for (int m = 0; m < TX / 64; ++m) {
            const int lj = tx + 64 * m;
            const int i = gy0 + li;
            const int j = gx0 + lj;
            const int r = li + 2;
            const int c = lj + 2;

            const float ex0 = EXAT(r, c, i);
            const float ey0 = EYAT(r, c, j);

            float exx, exy, eyy;
            // exx = d/di of phi_x
            if (i == 0)          exx = (EXAT(r + 1, c, 1) - ex0) * inv_d;
            else if (i == n - 1) exx = (ex0 - EXAT(r - 1, c, n - 2)) * inv_d;
            else                 exx = (EXAT(r + 1, c, i + 1) - EXAT(r - 1, c, i - 1)) * inv_2d;
            // exy = d/dj of phi_x
            if (j == 0)          exy = (EXAT(r, c + 1, i) - ex0) * inv_d;
            else if (j == n - 1) exy = (ex0 - EXAT(r, c - 1, i)) * inv_d;
            else                 exy = (EXAT(r, c + 1, i) - EXAT(r, c - 1, i)) * inv_2d;
            // eyy = d/dj of phi_y
            if (j == 0)          eyy = (EYAT(r, c + 1, 1) - ey0) * inv_d;
            else if (j == n - 1) eyy = (ey0 - EYAT(r, c - 1, n - 2)) * inv_d;
            else                 eyy = (EYAT(r, c + 1, j + 1) - EYAT(r, c - 1, j - 1)) * inv_2d;

            const float ev = fmaxf(sqrtf(ex0 * ex0 + ey0 * ey0), 4.6415888336e-6f);
            const float kc = (ex0 * ex0 * eyy - 2.0f * ex0 * ey0 * exy + ey0 * ey0 * exx)
                             / (ev * ev * ev);
            const float at = atanf(ev / (s[r][c] + 1e-6f));
            const float cc2 = fabsf(kc * at) - 2.8559933214452666f;  // pi/1.1
            float v = fmaxf(cc2, 0.0f);        // fmax drops NaN -> nansum
            if (isnan(v)) v = 0.0f;            // belt-and-braces
            acc += v;
        }
    }

    // ---- reduction: wave (64) -> block -> global atomic ----
    #pragma unroll
    for (int off = 32; off; off >>= 1)
        acc += __shfl_down(acc, off, 64);

    if (tx == 0) wsum[ty] = acc;
    __syncthreads();
    if (tx == 0 && ty == 0) {
        float t = wsum[0] + wsum[1] + wsum[2] + wsum[3];
        atomicAdd(out, t * d * d);   // ALPHA=1, scale by grid_size^2
    }
}

extern "C" void kernel_launch(void* const* d_in, const int* in_sizes, int n_in,
                              void* d_out, int out_size, void* d_ws, size_t ws_size,
                              hipStream_t stream) {
    const float* eps = (const float*)d_in[0];
    const float* gs  = (const float*)d_in[1];
    float* out = (float*)d_out;

    const long long tot = (long long)in_sizes[0];
    const int n = (int)(sqrt((double)tot) + 0.5);   // 8192

    hipMemsetAsync(out, 0, sizeof(float), stream);  // deterministic across replays

    dim3 block(64, 4);
    dim3 grid(n / TX, n / TY);
    fab_penalty_kernel<<<grid, block, 0, stream>>>(eps, gs, out, n);
}

// Round 2
// 281.522 us; speedup vs baseline: 1.6348x; 1.6348x over previous
//
#include <hip/hip_runtime.h>
#include <math.h>

// Fused fab_penalty_ls_curve: 13-point stencil over eps + global reduction.
// ref: phi_x,phi_y = gradient(eps); +1e-12; phi_xx,phi_xy = gradient(phi_x);
//      phi_yy = gradient(phi_y, axis=1);
//      k = (ex^2*eyy - 2 ex ey exy + ey^2 exx)/eps_v^3
//      cc = |k * atan(eps_v/(eps+1e-6))| - pi/1.1
//      out = nansum(max(cc,0) * d^2)
//
// R1 analysis: VALU-bound (HBM 4.6% of peak). Cost was edge-branch selects in
// every EXAT/EYAT + libm atanf + 2 IEEE divides. Fix: INTERIOR template path
// (branch-free central differences, SC cancels in 2nd derivs), polynomial
// atan with v_rcp range reduction, v_rcp/v_sqrt fast intrinsics.

constexpr int TX = 128;     // output tile cols per block
constexpr int TY = 32;      // output tile rows per block
constexpr int HW = TX + 4;  // 132 (halo 2 each side)
constexpr int HH = TY + 4;  // 36

__device__ __forceinline__ float fast_atan(float x) {
    // atan(x), full range. |err| ~1e-5 rad.
    const float ax = fabsf(x);
    const bool big = ax > 1.0f;
    const float t = big ? __builtin_amdgcn_rcpf(ax) : ax;   // t in [0,1]
    const float t2 = t * t;
    float p = fmaf(t2, -0.01172120f, 0.05265332f);
    p = fmaf(t2, p, -0.11643287f);
    p = fmaf(t2, p, 0.19354346f);
    p = fmaf(t2, p, -0.33262347f);
    p = fmaf(t2, p, 0.99997726f);
    p = t * p;
    float r = big ? (1.5707963268f - p) : p;
    return copysignf(r, x);
}

template <bool INTERIOR>
__global__ __launch_bounds__(256)
void fab_penalty_kernel(const float* __restrict__ eps,
                        const float* __restrict__ gs,
                        float* __restrict__ out, int n) {
    __shared__ float s[HH][HW];
    __shared__ float wsum[4];

    const float d       = *gs;
    const float inv_d   = 1.0f / d;
    const float inv_2d  = 0.5f / d;
    const float inv_4dd = inv_2d * inv_2d;

    const int tx = threadIdx.x;           // 0..63
    const int ty = threadIdx.y;           // 0..3
    const int gx0 = blockIdx.x * TX;
    const int gy0 = blockIdx.y * TY;

    // ---- load halo tile (clamped indices only guard OOB; clamped values are
    //      never consumed by the edge formulas) ----
    for (int r = ty; r < HH; r += 4) {
        int gi = gy0 - 2 + r;
        gi = min(max(gi, 0), n - 1);
        const float* row = eps + (size_t)gi * (size_t)n;
        for (int c = tx; c < HW; c += 64) {
            int gj = gx0 - 2 + c;
            gj = min(max(gj, 0), n - 1);
            s[r][c] = row[gj];
        }
    }
    __syncthreads();

    float acc = 0.0f;

    if (INTERIOR) {
        // Branch-free central differences. SC cancels in 2nd derivatives.
        #pragma unroll
        for (int k = 0; k < TY / 4; ++k) {
            const int r = ty + 4 * k + 2;
            #pragma unroll
            for (int m = 0; m < TX / 64; ++m) {
                const int c = tx + 64 * m + 2;

                const float c00 = s[r][c];
                const float ex = fmaf(s[r + 1][c] - s[r - 1][c], inv_2d, 1e-12f);
                const float ey = fmaf(s[r][c + 1] - s[r][c - 1], inv_2d, 1e-12f);
                const float exx = (s[r + 2][c] - 2.0f * c00 + s[r - 2][c]) * inv_4dd;
                const float eyy = (s[r][c + 2] - 2.0f * c00 + s[r][c - 2]) * inv_4dd;
                const float exy = ((s[r + 1][c + 1] - s[r - 1][c + 1])
                                 - (s[r + 1][c - 1] - s[r - 1][c - 1])) * inv_4dd;

                const float ev = fmaxf(__builtin_amdgcn_sqrtf(fmaf(ex, ex, ey * ey)),
                                       4.6415888336e-6f);
                const float num = fmaf(ex * ex, eyy,
                                  fmaf(-2.0f * ex * ey, exy, ey * ey * exx));
                const float kc = num * __builtin_amdgcn_rcpf(ev * ev * ev);
                const float at = fast_atan(ev * __builtin_amdgcn_rcpf(c00 + 1e-6f));
                float v = fmaxf(fabsf(kc * at) - 2.8559933214452666f, 0.0f);
                if (isnan(v)) v = 0.0f;   // nansum
                acc += v;
            }
        }
    } else {
        // General path with numpy edge_order=1 one-sided edge formulas.
        auto EXAT = [&](int r, int c, int i) -> float {
            float v;
            if (i == 0)          v = (s[r + 1][c] - s[r][c]) * inv_d;
            else if (i == n - 1) v = (s[r][c] - s[r - 1][c]) * inv_d;
            else                 v = (s[r + 1][c] - s[r - 1][c]) * inv_2d;
            return v + 1e-12f;
        };
        auto EYAT = [&](int r, int c, int j) -> float {
            float v;
            if (j == 0)          v = (s[r][c + 1] - s[r][c]) * inv_d;
            else if (j == n - 1) v = (s[r][c] - s[r][c - 1]) * inv_d;
            else                 v = (s[r][c + 1] - s[r][c - 1]) * inv_2d;
            return v + 1e-12f;
        };

        for (int k = 0; k < TY / 4; ++k) {
            const int li = ty + 4 * k;
            for (int m = 0; m < TX / 64; ++m) {
                const int lj = tx + 64 * m;
                const int i = gy0 + li;
                const int j = gx0 + lj;
                const int r = li + 2;
                const int c = lj + 2;

                const float ex0 = EXAT(r, c, i);
                const float ey0 = EYAT(r, c, j);

                float exx, exy, eyy;
                if (i == 0)          exx = (EXAT(r + 1, c, 1) - ex0) * inv_d;
                else if (i == n - 1) exx = (ex0 - EXAT(r - 1, c, n - 2)) * inv_d;
                else                 exx = (EXAT(r + 1, c, i + 1) - EXAT(r - 1, c, i - 1)) * inv_2d;
                if (j == 0)          exy = (EXAT(r, c + 1, i) - ex0) * inv_d;
                else if (j == n - 1) exy = (ex0 - EXAT(r, c - 1, i)) * inv_d;
                else                 exy = (EXAT(r, c + 1, i) - EXAT(r, c - 1, i)) * inv_2d;
                if (j == 0)          eyy = (EYAT(r, c + 1, 1) - ey0) * inv_d;
                else if (j == n - 1) eyy = (ey0 - EYAT(r, c - 1, n - 2)) * inv_d;
                else                 eyy = (EYAT(r, c + 1, j + 1) - EYAT(r, c - 1, j - 1)) * inv_2d;

                const float ev = fmaxf(__builtin_amdgcn_sqrtf(fmaf(ex0, ex0, ey0 * ey0)),
                                       4.6415888336e-6f);
                const float num = fmaf(ex0 * ex0, eyy,
                                  fmaf(-2.0f * ex0 * ey0, exy, ey0 * ey0 * exx));
                const float kc = num * __builtin_amdgcn_rcpf(ev * ev * ev);
                const float at = fast_atan(ev * __builtin_amdgcn_rcpf(s[r][c] + 1e-6f));
                float v = fmaxf(fabsf(kc * at) - 2.8559933214452666f, 0.0f);
                if (isnan(v)) v = 0.0f;
                acc += v;
            }
        }
    }

    // ---- reduction: wave (64) -> block -> global atomic ----
    #pragma unroll
    for (int off = 32; off; off >>= 1)
        acc += __shfl_down(acc, off, 64);

    if (tx == 0) wsum[ty] = acc;
    __syncthreads();
    if (tx == 0 && ty == 0) {
        float t = wsum[0] + wsum[1] + wsum[2] + wsum[3];
        atomicAdd(out, t * d * d);   // ALPHA=1, scale by grid_size^2
    }
}

extern "C" void kernel_launch(void* const* d_in, const int* in_sizes, int n_in,
                              void* d_out, int out_size, void* d_ws, size_t ws_size,
                              hipStream_t stream) {
    const float* eps = (const float*)d_in[0];
    const float* gs  = (const float*)d_in[1];
    float* out = (float*)d_out;

    const long long tot = (long long)in_sizes[0];
    const int n = (int)(sqrt((double)tot) + 0.5);   // 8192

    hipMemsetAsync(out, 0, sizeof(float), stream);

    const int gbx = n / TX;   // 64
    const int gby = n / TY;   // 256
    dim3 block(64, 4);

    // Interior blocks: bx in [1, gbx-2], by in [1, gby-2] — no grid-edge rows
    // or cols. Launch them as one dense grid with offset; edge frame as a
    // second kernel over the remaining blocks.
    dim3 ginner(gbx - 2, gby - 2);

    // Shift interior grid by (1,1) via a wrapper-free trick: launch full grid
    // for the edge kernel but skip interior? Simpler: two launches.
    // 1) interior: remap blockIdx -> (bx+1, by+1) using a tiny lambda kernel
    //    is not possible; instead launch interior kernel on full grid minus
    //    frame by passing the offset through grid dims only. We handle the
    //    offset inside by using blockIdx + 1.
    // (see fab_penalty_inner below)
    extern __global__ void fab_penalty_inner(const float*, const float*, float*, int);
    hipLaunchKernelGGL(fab_penalty_inner, ginner, block, 0, stream, eps, gs, out, n);

    // 2) frame: 2 block-rows + 2 block-cols
    dim3 gframe(2 * gbx + 2 * (gby - 2), 1);
    extern __global__ void fab_penalty_frame(const float*, const float*, float*, int);
    hipLaunchKernelGGL(fab_penalty_frame, gframe, block, 0, stream, eps, gs, out, n);
}

// Interior wrapper: blockIdx shifted by (1,1), guaranteed no grid edges.
__global__ __launch_bounds__(256)
void fab_penalty_inner(const float* __restrict__ eps,
                       const float* __restrict__ gs,
                       float* __restrict__ out, int n) {
    __shared__ float s[HH][HW];
    __shared__ float wsum[4];

    const float d       = *gs;
    const float inv_2d  = 0.5f / d;
    const float inv_4dd = inv_2d * inv_2d;

    const int tx = threadIdx.x;
    const int ty = threadIdx.y;
    const int gx0 = (blockIdx.x + 1) * TX;
    const int gy0 = (blockIdx.y + 1) * TY;

    for (int r = ty; r < HH; r += 4) {
        const float* row = eps + (size_t)(gy0 - 2 + r) * (size_t)n;
        for (int c = tx; c < HW; c += 64)
            s[r][c] = row[gx0 - 2 + c];
    }
    __syncthreads();

    float acc = 0.0f;
    #pragma unroll
    for (int k = 0; k < TY / 4; ++k) {
        const int r = ty + 4 * k + 2;
        #pragma unroll
        for (int m = 0; m < TX / 64; ++m) {
            const int c = tx + 64 * m + 2;

            const float c00 = s[r][c];
            const float ex = fmaf(s[r + 1][c] - s[r - 1][c], inv_2d, 1e-12f);
            const float ey = fmaf(s[r][c + 1] - s[r][c - 1], inv_2d, 1e-12f);
            const float exx = (s[r + 2][c] - 2.0f * c00 + s[r - 2][c]) * inv_4dd;
            const float eyy = (s[r][c + 2] - 2.0f * c00 + s[r][c - 2]) * inv_4dd;
            const float exy = ((s[r + 1][c + 1] - s[r - 1][c + 1])
                             - (s[r + 1][c - 1] - s[r - 1][c - 1])) * inv_4dd;

            const float ev = fmaxf(__builtin_amdgcn_sqrtf(fmaf(ex, ex, ey * ey)),
                                   4.6415888336e-6f);
            const float num = fmaf(ex * ex, eyy,
                              fmaf(-2.0f * ex * ey, exy, ey * ey * exx));
            const float kc = num * __builtin_amdgcn_rcpf(ev * ev * ev);
            const float at = fast_atan(ev * __builtin_amdgcn_rcpf(c00 + 1e-6f));
            float v = fmaxf(fabsf(kc * at) - 2.8559933214452666f, 0.0f);
            if (isnan(v)) v = 0.0f;
            acc += v;
        }
    }

    #pragma unroll
    for (int off = 32; off; off >>= 1)
        acc += __shfl_down(acc, off, 64);
    if (tx == 0) wsum[ty] = acc;
    __syncthreads();
    if (tx == 0 && ty == 0)
        atomicAdd(out, (wsum[0] + wsum[1] + wsum[2] + wsum[3]) * d * d);
}

// Frame wrapper: enumerate the boundary blocks of the (gbx x gby) grid and
// run the general (edge-correct) path via the templated kernel body.
__global__ __launch_bounds__(256)
void fab_penalty_frame(const float* __restrict__ eps,
                       const float* __restrict__ gs,
                       float* __restrict__ out, int n) {
    const int gbx = n / TX;
    const int gby = n / TY;
    // map linear frame index -> (bx, by)
    int id = blockIdx.x;
    int bx, by;
    if (id < gbx)                { bx = id;                by = 0; }
    else if (id < 2 * gbx)       { bx = id - gbx;          by = gby - 1; }
    else {
        int r = id - 2 * gbx;    // 0 .. 2*(gby-2)-1
        by = 1 + (r >> 1);
        bx = (r & 1) ? (gbx - 1) : 0;
    }

    __shared__ float s[HH][HW];
    __shared__ float wsum[4];

    const float d      = *gs;
    const float inv_d  = 1.0f / d;
    const float inv_2d = 0.5f / d;

    const int tx = threadIdx.x;
    const int ty = threadIdx.y;
    const int gx0 = bx * TX;
    const int gy0 = by * TY;

    for (int r = ty; r < HH; r += 4) {
        int gi = min(max(gy0 - 2 + r, 0), n - 1);
        const float* row = eps + (size_t)gi * (size_t)n;
        for (int c = tx; c < HW; c += 64) {
            int gj = min(max(gx0 - 2 + c, 0), n - 1);
            s[r][c] = row[gj];
        }
    }
    __syncthreads();

    auto EXAT = [&](int r, int c, int i) -> float {
        float v;
        if (i == 0)          v = (s[r + 1][c] - s[r][c]) * inv_d;
        else if (i == n - 1) v = (s[r][c] - s[r - 1][c]) * inv_d;
        else                 v = (s[r + 1][c] - s[r - 1][c]) * inv_2d;
        return v + 1e-12f;
    };
    auto EYAT = [&](int r, int c, int j) -> float {
        float v;
        if (j == 0)          v = (s[r][c + 1] - s[r][c]) * inv_d;
        else if (j == n - 1) v = (s[r][c] - s[r][c - 1]) * inv_d;
        else                 v = (s[r][c + 1] - s[r][c - 1]) * inv_2d;
        return v + 1e-12f;
    };

    float acc = 0.0f;
    for (int k = 0; k < TY / 4; ++k) {
        const int li = ty + 4 * k;
        for (int m = 0; m < TX / 64; ++m) {
            const int lj = tx + 64 * m;
            const int i = gy0 + li;
            const int j = gx0 + lj;
            const int r = li + 2;
            const int c = lj + 2;

            const float ex0 = EXAT(r, c, i);
            const float ey0 = EYAT(r, c, j);

            float exx, exy, eyy;
            if (i == 0)          exx = (EXAT(r + 1, c, 1) - ex0) * inv_d;
            else if (i == n - 1) exx = (ex0 - EXAT(r - 1, c, n - 2)) * inv_d;
            else                 exx = (EXAT(r + 1, c, i + 1) - EXAT(r - 1, c, i - 1)) * inv_2d;
            if (j == 0)          exy = (EXAT(r, c + 1, i) - ex0) * inv_d;
            else if (j == n - 1) exy = (ex0 - EXAT(r, c - 1, i)) * inv_d;
            else                 exy = (EXAT(r, c + 1, i) - EXAT(r, c - 1, i)) * inv_2d;
            if (j == 0)          eyy = (EYAT(r, c + 1, 1) - ey0) * inv_d;
            else if (j == n - 1) eyy = (ey0 - EYAT(r, c - 1, n - 2)) * inv_d;
            else                 eyy = (EYAT(r, c + 1, j + 1) - EYAT(r, c - 1, j - 1)) * inv_2d;

            const float ev = fmaxf(__builtin_amdgcn_sqrtf(fmaf(ex0, ex0, ey0 * ey0)),
                                   4.6415888336e-6f);
            const float num = fmaf(ex0 * ex0, eyy,
                              fmaf(-2.0f * ex0 * ey0, exy, ey0 * ey0 * exx));
            const float kc = num * __builtin_amdgcn_rcpf(ev * ev * ev);
            const float at = fast_atan(ev * __builtin_amdgcn_rcpf(s[r][c] + 1e-6f));
            float v = fmaxf(fabsf(kc * at) - 2.8559933214452666f, 0.0f);
            if (isnan(v)) v = 0.0f;
            acc += v;
        }
    }

    #pragma unroll
    for (int off = 32; off; off >>= 1)
        acc += __shfl_down(acc, off, 64);
    if (tx == 0) wsum[ty] = acc;
    __syncthreads();
    if (tx == 0 && ty == 0)
        atomicAdd(out, (wsum[0] + wsum[1] + wsum[2] + wsum[3]) * d * d);
}

// Round 3
// 229.875 us; speedup vs baseline: 2.0022x; 1.2247x over previous
//
#include <hip/hip_runtime.h>
#include <math.h>

// Fused fab_penalty_ls_curve: 13-point stencil over eps + global reduction.
// R2 analysis: VALU-inst-bound at 10.4 cyc/el vs ~2 cyc math floor. Overhead
// was per-element scalar LDS reads + addressing + low ILP (VGPR=32).
// R3 design: no LDS. Each thread owns 4 consecutive cols, sweeps a 64-row
// strip. Per row: 8 global dwordx4 loads (SGPR row base + fixed voffset,
// L1/L2-hot), double-buffered stages, statically-unrolled float4 math.
// Domain border (2-wide, 98k elements) handled by one extra blockIdx.y row
// of blocks running the general edge_order=1 path.

typedef float f4 __attribute__((ext_vector_type(4), aligned(4)));

constexpr float SCF  = 1e-12f;
constexpr float EVF  = 4.6415888336e-6f;        // 1e-32^(1/6)
constexpr float PID  = 2.8559933214452666f;     // pi/1.1

__device__ __forceinline__ float fast_atan(float x) {
    // atan(x), full range, |err| ~1e-5 rad.
    const float ax = fabsf(x);
    const bool big = ax > 1.0f;
    const float t = big ? __builtin_amdgcn_rcpf(ax) : ax;   // t in [0,1]
    const float t2 = t * t;
    float p = fmaf(t2, -0.01172120f, 0.05265332f);
    p = fmaf(t2, p, -0.11643287f);
    p = fmaf(t2, p, 0.19354346f);
    p = fmaf(t2, p, -0.33262347f);
    p = fmaf(t2, p, 0.99997726f);
    p = t * p;
    float r = big ? (1.5707963268f - p) : p;
    return copysignf(r, x);
}

// ---- inner-path stencil stage: 5-row x 8-col window for 4 outputs ----
struct Stage {
    f4 m2, m1a, m1b, z0a, z0b, p1a, p1b, p2;
};

__device__ __forceinline__ void load_stage(Stage& S, const float* __restrict__ eps,
                                           int n, int i, int j) {
    // output row i, output cols j..j+3 (all central-difference territory)
    const float* rb = eps + (size_t)(i - 2) * (size_t)n;
    S.m2  = *(const f4*)(rb + j);                 // row i-2, cols j..j+3
    S.m1a = *(const f4*)(rb + n + (j - 1));       // row i-1, cols j-1..j+2
    S.m1b = *(const f4*)(rb + n + (j + 3));       // row i-1, cols j+3..j+6
    S.z0a = *(const f4*)(rb + 2 * n + (j - 2));   // row i,   cols j-2..j+1
    S.z0b = *(const f4*)(rb + 2 * n + (j + 2));   // row i,   cols j+2..j+5
    S.p1a = *(const f4*)(rb + 3 * n + (j - 1));   // row i+1
    S.p1b = *(const f4*)(rb + 3 * n + (j + 3));
    S.p2  = *(const f4*)(rb + 4 * n + j);         // row i+2, cols j..j+3
}

__device__ __forceinline__ float compute_stage(const Stage& S, float inv_2d,
                                               float inv_4dd, bool valid) {
    auto W0 = [&](int k) { return k < 4 ? S.z0a[k] : S.z0b[k - 4]; }; // col j-2+k
    auto M1 = [&](int k) { return k < 4 ? S.m1a[k] : S.m1b[k - 4]; }; // col j-1+k
    auto P1 = [&](int k) { return k < 4 ? S.p1a[k] : S.p1b[k - 4]; };

    float part = 0.0f;
    #pragma unroll
    for (int q = 0; q < 4; ++q) {
        const float c00 = W0(q + 2);
        const float c2  = c00 + c00;
        const float ex  = fmaf(P1(q + 1) - M1(q + 1), inv_2d, SCF);
        const float ey  = fmaf(W0(q + 3) - W0(q + 1), inv_2d, SCF);
        const float exx = (S.p2[q] - c2 + S.m2[q]) * inv_4dd;
        const float eyy = (W0(q + 4) - c2 + W0(q)) * inv_4dd;
        const float exy = ((P1(q + 2) - M1(q + 2)) - (P1(q) - M1(q))) * inv_4dd;

        const float ev = fmaxf(__builtin_amdgcn_sqrtf(fmaf(ex, ex, ey * ey)), EVF);
        const float num = fmaf(ex * ex, eyy,
                          fmaf(-2.0f * ex * ey, exy, ey * ey * exx));
        const float kc = num * __builtin_amdgcn_rcpf(ev * ev * ev);
        const float at = fast_atan(ev * __builtin_amdgcn_rcpf(c00 + 1e-6f));
        float v = fmaxf(fabsf(kc * at) - PID, 0.0f);
        if (isnan(v)) v = 0.0f;   // nansum
        part += v;
    }
    return valid ? part : 0.0f;
}

// ---- frame-path helpers: numpy edge_order=1 gradients on global memory ----
__device__ __forceinline__ float eg(const float* __restrict__ e, int n, int i, int j) {
    return e[(size_t)i * (size_t)n + j];
}
__device__ __forceinline__ float gex(const float* __restrict__ e, int n, int i, int j,
                                     float inv_d, float inv_2d) {
    float v;
    if (i == 0)          v = (eg(e, n, 1, j) - eg(e, n, 0, j)) * inv_d;
    else if (i == n - 1) v = (eg(e, n, n - 1, j) - eg(e, n, n - 2, j)) * inv_d;
    else                 v = (eg(e, n, i + 1, j) - eg(e, n, i - 1, j)) * inv_2d;
    return v + SCF;
}
__device__ __forceinline__ float gey(const float* __restrict__ e, int n, int i, int j,
                                     float inv_d, float inv_2d) {
    float v;
    if (j == 0)          v = (eg(e, n, i, 1) - eg(e, n, i, 0)) * inv_d;
    else if (j == n - 1) v = (eg(e, n, i, n - 1) - eg(e, n, i, n - 2)) * inv_d;
    else                 v = (eg(e, n, i, j + 1) - eg(e, n, i, j - 1)) * inv_2d;
    return v + SCF;
}

__global__ __launch_bounds__(256, 3)
void fab_fused(const float* __restrict__ eps, const float* __restrict__ gs,
               float* __restrict__ out, int n, int G, int nstrip, int rs) {
    const float d       = *gs;
    const float inv_2d  = 0.5f / d;
    const float inv_4dd = inv_2d * inv_2d;

    float acc = 0.0f;

    if ((int)blockIdx.y < nstrip) {
        // ================= inner (central-difference) path =================
        const int gg    = blockIdx.x * 256 + threadIdx.x;    // col group id
        const bool valid = (gg >= 1) && (gg <= G);
        const int gc    = min(max(gg, 1), G);
        const int j     = 4 * gc;                            // cols j..j+3
        const int i0    = 2 + rs * blockIdx.y;
        const int count = min(rs, (n - 2) - i0);             // rows this strip

        Stage A, B;
        load_stage(A, eps, n, i0, j);
        int r = 0;
        for (; r + 2 < count; r += 2) {
            load_stage(B, eps, n, i0 + r + 1, j);
            acc += compute_stage(A, inv_2d, inv_4dd, valid);
            load_stage(A, eps, n, i0 + r + 2, j);
            acc += compute_stage(B, inv_2d, inv_4dd, valid);
        }
        if (r + 2 == count) {
            load_stage(B, eps, n, i0 + count - 1, j);
            acc += compute_stage(A, inv_2d, inv_4dd, valid);
            acc += compute_stage(B, inv_2d, inv_4dd, valid);
        } else {
            // odd remainder: exactly one row left in A
            acc += compute_stage(A, inv_2d, inv_4dd, valid);
        }
    } else {
        // ================= frame (edge_order=1 one-sided) path =============
        // rows {0,1,n-2,n-1} x all cols  +  cols {0..3, n-4..n-1} x rows [2,n-2)
        const float inv_d = inv_2d + inv_2d;
        const int nfr = 4 * n + 8 * (n - 4);
        const int tid = blockIdx.x * 256 + threadIdx.x;
        const int nth = gridDim.x * 256;

        for (int idx = tid; idx < nfr; idx += nth) {
            int i, j;
            if (idx < 4 * n) {
                const int rr = (idx >= n) + (idx >= 2 * n) + (idx >= 3 * n);
                j = idx - rr * n;
                i = (rr < 2) ? rr : (n - 4) + rr;            // 0,1,n-2,n-1
            } else {
                const int t = idx - 4 * n;
                i = 2 + (t >> 3);                            // rows 2..n-3
                const int cc = t & 7;
                j = (cc < 4) ? cc : (n - 8) + cc;            // 0..3, n-4..n-1
            }

            const float ex0 = gex(eps, n, i, j, inv_d, inv_2d);
            const float ey0 = gey(eps, n, i, j, inv_d, inv_2d);

            float exx, exy, eyy;
            if (i == 0)
                exx = (gex(eps, n, 1, j, inv_d, inv_2d) - ex0) * inv_d;
            else if (i == n - 1)
                exx = (ex0 - gex(eps, n, n - 2, j, inv_d, inv_2d)) * inv_d;
            else
                exx = (gex(eps, n, i + 1, j, inv_d, inv_2d)
                     - gex(eps, n, i - 1, j, inv_d, inv_2d)) * inv_2d;

            if (j == 0)
                exy = (gex(eps, n, i, 1, inv_d, inv_2d) - ex0) * inv_d;
            else if (j == n - 1)
                exy = (ex0 - gex(eps, n, i, n - 2, inv_d, inv_2d)) * inv_d;
            else
                exy = (gex(eps, n, i, j + 1, inv_d, inv_2d)
                     - gex(eps, n, i, j - 1, inv_d, inv_2d)) * inv_2d;

            if (j == 0)
                eyy = (gey(eps, n, i, 1, inv_d, inv_2d) - ey0) * inv_d;
            else if (j == n - 1)
                eyy = (ey0 - gey(eps, n, i, n - 2, inv_d, inv_2d)) * inv_d;
            else
                eyy = (gey(eps, n, i, j + 1, inv_d, inv_2d)
                     - gey(eps, n, i, j - 1, inv_d, inv_2d)) * inv_2d;

            const float ev = fmaxf(__builtin_amdgcn_sqrtf(fmaf(ex0, ex0, ey0 * ey0)), EVF);
            const float num = fmaf(ex0 * ex0, eyy,
                              fmaf(-2.0f * ex0 * ey0, exy, ey0 * ey0 * exx));
            const float kc = num * __builtin_amdgcn_rcpf(ev * ev * ev);
            const float at = fast_atan(ev * __builtin_amdgcn_rcpf(eg(eps, n, i, j) + 1e-6f));
            float v = fmaxf(fabsf(kc * at) - PID, 0.0f);
            if (isnan(v)) v = 0.0f;
            acc += v;
        }
    }

    // ---- per-wave reduction + one atomic per wave ----
    #pragma unroll
    for (int off = 32; off; off >>= 1)
        acc += __shfl_down(acc, off, 64);
    if ((threadIdx.x & 63) == 0)
        atomicAdd(out, acc * d * d);
}

extern "C" void kernel_launch(void* const* d_in, const int* in_sizes, int n_in,
                              void* d_out, int out_size, void* d_ws, size_t ws_size,
                              hipStream_t stream) {
    const float* eps = (const float*)d_in[0];
    const float* gs  = (const float*)d_in[1];
    float* out = (float*)d_out;

    const long long tot = (long long)in_sizes[0];
    const int n = (int)(sqrt((double)tot) + 0.5);   // 8192

    hipMemsetAsync(out, 0, sizeof(float), stream);

    const int G  = (n - 8) / 4;          // interior col groups: cols [4, n-4)
    const int RS = 64;                   // rows per strip
    const int nstrip = (n - 4 + RS - 1) / RS;   // interior rows [2, n-2)

    dim3 block(256, 1);
    dim3 grid(n / 1024, nstrip + 1);     // last y-row of blocks = frame path
    fab_fused<<<grid, block, 0, stream>>>(eps, gs, out, n, G, nstrip, RS);
}

// Round 4
// 102.189 us; speedup vs baseline: 4.5039x; 2.2495x over previous
//
#include <hip/hip_runtime.h>
#include <math.h>

// Fused fab_penalty_ls_curve: 13-point stencil over eps + global reduction.
// R3 post-mortem: latency-bound (occupancy 23%, VALU 32%, HBM 10%) — loads
// issued in the same phase that consumes them, tiny grid, 8 loads/row-step.
// R4: 6-deep register row rotation (load only the new row, 2 dwordx4 per
// row-step, one phase ahead of its consumer), 32-row strips (2112 blocks),
// leaner math (one-rcp |atan|, no isnan, no copysign), block-level atomic.

typedef float f4 __attribute__((ext_vector_type(4), aligned(4)));

constexpr float SCF = 1e-12f;
constexpr float EVF = 4.6415888336e-6f;        // 1e-32^(1/6)
constexpr float PID = 2.8559933214452666f;     // pi/1.1
constexpr int   RS  = 32;                      // rows per strip
constexpr int   FEXTRA = 8;                    // grid.y rows for frame path

struct Row { f4 lo, hi; };                     // cols j-2..j+1, j+2..j+5

__device__ __forceinline__ float C(const Row& r, int k) {
    return k < 4 ? r.lo[k] : r.hi[k - 4];      // k is compile-time after unroll
}
__device__ __forceinline__ void load_row(Row& r, const float* p) {
    r.lo = *(const f4*)p;
    r.hi = *(const f4*)(p + 4);
}

// ---- per-output-row math: 4 elements, pure central differences ----
__device__ __forceinline__ float compute_row(const Row& rm2, const Row& rm1,
                                             const Row& rz,  const Row& rp1,
                                             const Row& rp2, float inv_2d,
                                             float inv_4dd, bool valid) {
    float dif[6];                              // rp1-rm1 at cols j-1..j+4
    #pragma unroll
    for (int k = 0; k < 6; ++k) dif[k] = C(rp1, k + 1) - C(rm1, k + 1);

    float part = 0.0f;
    #pragma unroll
    for (int q = 0; q < 4; ++q) {
        const float c00 = C(rz, q + 2);
        const float ex  = fmaf(dif[q + 1], inv_2d, SCF);
        const float ey  = fmaf(C(rz, q + 3) - C(rz, q + 1), inv_2d, SCF);
        const float exx = fmaf(-2.0f, c00, C(rp2, q + 2) + C(rm2, q + 2)) * inv_4dd;
        const float eyy = fmaf(-2.0f, c00, C(rz, q + 4) + C(rz, q)) * inv_4dd;
        const float exy = (dif[q + 2] - dif[q]) * inv_4dd;

        const float s2 = fmaf(ex, ex, ey * ey);
        const float ev = fmaxf(__builtin_amdgcn_sqrtf(s2), EVF);
        const float num = fmaf(ex * ex, eyy,
                          fmaf(-2.0f * ex * ey, exy, ey * ey * exx));
        const float kabs = fabsf(num) * __builtin_amdgcn_rcpf(ev * ev * ev);

        // |atan(ev / (c00+1e-6))| = atan(ev/|w|): min/max reduction, 1 rcp
        const float aw = fabsf(c00 + 1e-6f);
        const float mx = fmaxf(ev, aw);
        const float mn = fminf(ev, aw);
        const float t  = mn * __builtin_amdgcn_rcpf(mx);
        const float t2 = t * t;
        float pl = fmaf(t2, -0.01172120f, 0.05265332f);
        pl = fmaf(t2, pl, -0.11643287f);
        pl = fmaf(t2, pl, 0.19354346f);
        pl = fmaf(t2, pl, -0.33262347f);
        pl = fmaf(t2, pl, 0.99997726f);
        pl *= t;
        const float at = (ev > aw) ? (1.5707963268f - pl) : pl;

        // fmaxf(NaN,0)=0 (IEEE maxnum) implements nansum
        part += fmaxf(fmaf(kabs, at, -PID), 0.0f);
    }
    return valid ? part : 0.0f;
}

// ---- frame-path helpers: numpy edge_order=1 gradients on global memory ----
__device__ __forceinline__ float eg(const float* __restrict__ e, int n, int i, int j) {
    return e[(size_t)i * (size_t)n + j];
}
__device__ __forceinline__ float gex(const float* __restrict__ e, int n, int i, int j,
                                     float inv_d, float inv_2d) {
    float v;
    if (i == 0)          v = (eg(e, n, 1, j) - eg(e, n, 0, j)) * inv_d;
    else if (i == n - 1) v = (eg(e, n, n - 1, j) - eg(e, n, n - 2, j)) * inv_d;
    else                 v = (eg(e, n, i + 1, j) - eg(e, n, i - 1, j)) * inv_2d;
    return v + SCF;
}
__device__ __forceinline__ float gey(const float* __restrict__ e, int n, int i, int j,
                                     float inv_d, float inv_2d) {
    float v;
    if (j == 0)          v = (eg(e, n, i, 1) - eg(e, n, i, 0)) * inv_d;
    else if (j == n - 1) v = (eg(e, n, i, n - 1) - eg(e, n, i, n - 2)) * inv_d;
    else                 v = (eg(e, n, i, j + 1) - eg(e, n, i, j - 1)) * inv_2d;
    return v + SCF;
}

__global__ __launch_bounds__(256, 4)
void fab_fused(const float* __restrict__ eps, const float* __restrict__ gs,
               float* __restrict__ out, int n, int G, int nstrip) {
    const float d       = *gs;
    const float inv_2d  = 0.5f / d;
    const float inv_4dd = inv_2d * inv_2d;

    float acc = 0.0f;

    if ((int)blockIdx.y < nstrip) {
        // ================= inner (central-difference) path =================
        const int gg = blockIdx.x * 256 + threadIdx.x;     // col group id
        const bool valid = (gg >= 1) && (gg <= G);
        const int gc = min(max(gg, 1), G);
        const int j  = 4 * gc;                             // cols j..j+3
        const int i0 = 2 + RS * blockIdx.y;
        const int count = min(RS, (n - 2) - i0);           // rows this strip
        const float* pj = eps + (j - 2);

        Row r0, r1, r2, r3, r4, r5;
        // prologue: rows i0-2 .. i0+2 -> slots r0..r4
        load_row(r0, pj + (size_t)(i0 - 2) * (size_t)n);
        load_row(r1, pj + (size_t)(i0 - 1) * (size_t)n);
        load_row(r2, pj + (size_t)(i0    ) * (size_t)n);
        load_row(r3, pj + (size_t)(i0 + 1) * (size_t)n);
        load_row(r4, pj + (size_t)(i0 + 2) * (size_t)n);

        // phase k: compute output row i0+k (rows i0+k-2..i0+k+2 resident),
        // and prefetch row i0+k+3 for phase k+1. Loads run one phase ahead.
        #define PHASE(q, Rm2, Rm1, Rz, Rp1, Rp2, Rld)                         \
        {                                                                     \
            const int k = kbase + (q);                                        \
            if (k < count) {                                                  \
                if (k <= count - 2)                                           \
                    load_row(Rld, pj + (size_t)(i0 + k + 3) * (size_t)n);     \
                acc += compute_row(Rm2, Rm1, Rz, Rp1, Rp2,                    \
                                   inv_2d, inv_4dd, valid);                   \
            }                                                                 \
        }

        #pragma unroll 1
        for (int kbase = 0; kbase < RS; kbase += 6) {
            PHASE(0, r0, r1, r2, r3, r4, r5);
            PHASE(1, r1, r2, r3, r4, r5, r0);
            PHASE(2, r2, r3, r4, r5, r0, r1);
            PHASE(3, r3, r4, r5, r0, r1, r2);
            PHASE(4, r4, r5, r0, r1, r2, r3);
            PHASE(5, r5, r0, r1, r2, r3, r4);
        }
        #undef PHASE
    } else {
        // ================= frame (edge_order=1 one-sided) path =============
        // rows {0,1,n-2,n-1} x all cols + cols {0..3, n-4..n-1} x rows [2,n-2)
        const float inv_d = inv_2d + inv_2d;
        const int nfr = 4 * n + 8 * (n - 4);
        const int fb  = (int)blockIdx.y - nstrip;                 // 0..FEXTRA-1
        const int tid = (fb * gridDim.x + blockIdx.x) * 256 + threadIdx.x;
        const int nth = FEXTRA * gridDim.x * 256;

        for (int idx = tid; idx < nfr; idx += nth) {
            int i, j;
            if (idx < 4 * n) {
                const int rr = (idx >= n) + (idx >= 2 * n) + (idx >= 3 * n);
                j = idx - rr * n;
                i = (rr < 2) ? rr : (n - 4) + rr;                 // 0,1,n-2,n-1
            } else {
                const int t = idx - 4 * n;
                i = 2 + (t >> 3);                                 // rows 2..n-3
                const int cc = t & 7;
                j = (cc < 4) ? cc : (n - 8) + cc;                 // 0..3, n-4..n-1
            }

            const float ex0 = gex(eps, n, i, j, inv_d, inv_2d);
            const float ey0 = gey(eps, n, i, j, inv_d, inv_2d);

            float exx, exy, eyy;
            if (i == 0)
                exx = (gex(eps, n, 1, j, inv_d, inv_2d) - ex0) * inv_d;
            else if (i == n - 1)
                exx = (ex0 - gex(eps, n, n - 2, j, inv_d, inv_2d)) * inv_d;
            else
                exx = (gex(eps, n, i + 1, j, inv_d, inv_2d)
                     - gex(eps, n, i - 1, j, inv_d, inv_2d)) * inv_2d;

            if (j == 0)
                exy = (gex(eps, n, i, 1, inv_d, inv_2d) - ex0) * inv_d;
            else if (j == n - 1)
                exy = (ex0 - gex(eps, n, i, n - 2, inv_d, inv_2d)) * inv_d;
            else
                exy = (gex(eps, n, i, j + 1, inv_d, inv_2d)
                     - gex(eps, n, i, j - 1, inv_d, inv_2d)) * inv_2d;

            if (j == 0)
                eyy = (gey(eps, n, i, 1, inv_d, inv_2d) - ey0) * inv_d;
            else if (j == n - 1)
                eyy = (ey0 - gey(eps, n, i, n - 2, inv_d, inv_2d)) * inv_d;
            else
                eyy = (gey(eps, n, i, j + 1, inv_d, inv_2d)
                     - gey(eps, n, i, j - 1, inv_d, inv_2d)) * inv_2d;

            const float ev = fmaxf(__builtin_amdgcn_sqrtf(fmaf(ex0, ex0, ey0 * ey0)), EVF);
            const float num = fmaf(ex0 * ex0, eyy,
                              fmaf(-2.0f * ex0 * ey0, exy, ey0 * ey0 * exx));
            const float kabs = fabsf(num) * __builtin_amdgcn_rcpf(ev * ev * ev);

            const float aw = fabsf(eg(eps, n, i, j) + 1e-6f);
            const float mx = fmaxf(ev, aw);
            const float mn = fminf(ev, aw);
            const float t  = mn * __builtin_amdgcn_rcpf(mx);
            const float t2 = t * t;
            float pl = fmaf(t2, -0.01172120f, 0.05265332f);
            pl = fmaf(t2, pl, -0.11643287f);
            pl = fmaf(t2, pl, 0.19354346f);
            pl = fmaf(t2, pl, -0.33262347f);
            pl = fmaf(t2, pl, 0.99997726f);
            pl *= t;
            const float at = (ev > aw) ? (1.5707963268f - pl) : pl;

            acc += fmaxf(fmaf(kabs, at, -PID), 0.0f);
        }
    }

    // ---- reduction: wave -> block (LDS) -> one atomic per block ----
    __shared__ float wsum[4];
    #pragma unroll
    for (int off = 32; off; off >>= 1)
        acc += __shfl_down(acc, off, 64);
    if ((threadIdx.x & 63) == 0) wsum[threadIdx.x >> 6] = acc;
    __syncthreads();
    if (threadIdx.x == 0)
        atomicAdd(out, (wsum[0] + wsum[1] + wsum[2] + wsum[3]) * d * d);
}

extern "C" void kernel_launch(void* const* d_in, const int* in_sizes, int n_in,
                              void* d_out, int out_size, void* d_ws, size_t ws_size,
                              hipStream_t stream) {
    const float* eps = (const float*)d_in[0];
    const float* gs  = (const float*)d_in[1];
    float* out = (float*)d_out;

    const long long tot = (long long)in_sizes[0];
    const int n = (int)(sqrt((double)tot) + 0.5);   // 8192

    hipMemsetAsync(out, 0, sizeof(float), stream);

    const int G = (n - 8) / 4;                      // interior col groups
    const int nstrip = (n - 4 + RS - 1) / RS;       // interior rows [2, n-2)

    dim3 block(256, 1);
    dim3 grid(n / 1024, nstrip + FEXTRA);           // last FEXTRA y-rows: frame
    fab_fused<<<grid, block, 0, stream>>>(eps, gs, out, n, G, nstrip);
}

// Round 5
// 92.156 us; speedup vs baseline: 4.9942x; 1.1089x over previous
//
#include <hip/hip_runtime.h>
#include <math.h>

// Fused fab_penalty_ls_curve: 13-point stencil over eps + global reduction.
// R4 post-mortem: 102 us; implied VALUBusy ~37%, HBM ~45% -> issue/latency
// bound. R5: pack TWO OUTPUT ROWS per float2 lane so the whole stencil chain
// maps to v_pk_*_f32 (full-rate packed fp32 on gfx950). Column shifts stay
// pair-aligned (no shuffles); 8-slot row rotation, 2 rows loaded per phase
// one full phase ahead of use via incrementing pointer.

typedef float f2 __attribute__((ext_vector_type(2)));
typedef float f4 __attribute__((ext_vector_type(4), aligned(4)));

constexpr float SCF = 1e-12f;
constexpr float EVF = 4.6415888336e-6f;        // 1e-32^(1/6)
constexpr float PID = 2.8559933214452666f;     // pi/1.1
constexpr float PIH = 1.5707963268f;
constexpr int   RS  = 32;                      // rows per strip (even)
constexpr int   FEXTRA = 8;                    // grid.y rows for frame path

struct Row { f4 lo, hi; };                     // cols j-2..j+1, j+2..j+5

__device__ __forceinline__ float C(const Row& r, int k) {
    return k < 4 ? r.lo[k] : r.hi[k - 4];      // k compile-time after unroll
}
__device__ __forceinline__ void load_row(Row& r, const float* p) {
    r.lo = *(const f4*)p;
    r.hi = *(const f4*)(p + 4);
}
__device__ __forceinline__ f2 mk(float a, float b) { f2 v; v.x = a; v.y = b; return v; }
__device__ __forceinline__ f2 fma2(f2 a, f2 b, f2 c) { return __builtin_elementwise_fma(a, b, c); }
__device__ __forceinline__ f2 max2(f2 a, f2 b) { return __builtin_elementwise_max(a, b); }
__device__ __forceinline__ f2 min2(f2 a, f2 b) { return __builtin_elementwise_min(a, b); }
__device__ __forceinline__ f2 abs2(f2 a) { return __builtin_elementwise_abs(a); }
__device__ __forceinline__ f2 rcp2(f2 a) {
    return mk(__builtin_amdgcn_rcpf(a.x), __builtin_amdgcn_rcpf(a.y));
}
__device__ __forceinline__ f2 sqrt2(f2 a) {
    return mk(__builtin_amdgcn_sqrtf(a.x), __builtin_amdgcn_sqrtf(a.y));
}

// ---- packed math for output rows (i, i+1): R0..R5 = rows i-2 .. i+3 ----
__device__ __forceinline__ f2 compute_pair(const Row& R0, const Row& R1,
                                           const Row& R2, const Row& R3,
                                           const Row& R4, const Row& R5,
                                           f2 inv2d, f2 inv4dd) {
    f2 dif[6];                                 // (rp1-rm1) at cols j-1..j+4
    #pragma unroll
    for (int k = 0; k < 6; ++k)
        dif[k] = mk(C(R3, k + 1) - C(R1, k + 1),
                    C(R4, k + 1) - C(R2, k + 1));
    f2 Pz[8];                                  // center rows, cols j-2..j+5
    #pragma unroll
    for (int k = 0; k < 8; ++k)
        Pz[k] = mk(C(R2, k), C(R3, k));

    const f2 sc2 = mk(SCF, SCF);
    f2 part = mk(0.0f, 0.0f);
    #pragma unroll
    for (int q = 0; q < 4; ++q) {
        const f2 c00 = Pz[q + 2];
        const f2 ex  = fma2(dif[q + 1], inv2d, sc2);
        const f2 ey  = fma2(Pz[q + 3] - Pz[q + 1], inv2d, sc2);
        const f2 sxx = mk(C(R4, q + 2) + C(R0, q + 2),
                          C(R5, q + 2) + C(R1, q + 2));
        const f2 exx = (sxx - 2.0f * c00) * inv4dd;
        const f2 eyy = (Pz[q + 4] + Pz[q] - 2.0f * c00) * inv4dd;
        const f2 exy = (dif[q + 2] - dif[q]) * inv4dd;

        const f2 ev  = max2(sqrt2(fma2(ex, ex, ey * ey)), mk(EVF, EVF));
        const f2 num = fma2(ex * ex, eyy,
                       fma2(-2.0f * (ex * ey), exy, (ey * ey) * exx));
        const f2 kabs = abs2(num) * rcp2(ev * ev * ev);

        // |atan(ev/w)| = atan(ev/|w|): min/max range reduction, 1 rcp
        const f2 aw = abs2(c00 + 1e-6f);
        const f2 mx = max2(ev, aw);
        const f2 mn = min2(ev, aw);
        const f2 t  = mn * rcp2(mx);
        const f2 t2 = t * t;
        f2 pl = fma2(t2, mk(-0.01172120f, -0.01172120f), mk(0.05265332f, 0.05265332f));
        pl = fma2(t2, pl, mk(-0.11643287f, -0.11643287f));
        pl = fma2(t2, pl, mk(0.19354346f, 0.19354346f));
        pl = fma2(t2, pl, mk(-0.33262347f, -0.33262347f));
        pl = fma2(t2, pl, mk(0.99997726f, 0.99997726f));
        pl = pl * t;
        f2 at;
        at.x = (ev.x > aw.x) ? PIH - pl.x : pl.x;
        at.y = (ev.y > aw.y) ? PIH - pl.y : pl.y;

        // v_pk_max(NaN,0)=0 implements nansum
        part = part + max2(fma2(kabs, at, mk(-PID, -PID)), mk(0.0f, 0.0f));
    }
    return part;
}

// ---- frame-path helpers: numpy edge_order=1 gradients on global memory ----
__device__ __forceinline__ float eg(const float* __restrict__ e, int n, int i, int j) {
    return e[(size_t)i * (size_t)n + j];
}
__device__ __forceinline__ float gex(const float* __restrict__ e, int n, int i, int j,
                                     float inv_d, float inv_2d) {
    float v;
    if (i == 0)          v = (eg(e, n, 1, j) - eg(e, n, 0, j)) * inv_d;
    else if (i == n - 1) v = (eg(e, n, n - 1, j) - eg(e, n, n - 2, j)) * inv_d;
    else                 v = (eg(e, n, i + 1, j) - eg(e, n, i - 1, j)) * inv_2d;
    return v + SCF;
}
__device__ __forceinline__ float gey(const float* __restrict__ e, int n, int i, int j,
                                     float inv_d, float inv_2d) {
    float v;
    if (j == 0)          v = (eg(e, n, i, 1) - eg(e, n, i, 0)) * inv_d;
    else if (j == n - 1) v = (eg(e, n, i, n - 1) - eg(e, n, i, n - 2)) * inv_d;
    else                 v = (eg(e, n, i, j + 1) - eg(e, n, i, j - 1)) * inv_2d;
    return v + SCF;
}

__global__ __launch_bounds__(256, 4)
void fab_fused(const float* __restrict__ eps, const float* __restrict__ gs,
               float* __restrict__ out, int n, int G, int nstrip) {
    const float d       = *gs;
    const float inv_2d  = 0.5f / d;
    const float inv_4dd = inv_2d * inv_2d;

    float acc = 0.0f;

    if ((int)blockIdx.y < nstrip) {
        // ================= inner (central-difference) path =================
        const int gg = blockIdx.x * 256 + threadIdx.x;     // col group id
        const bool valid = (gg >= 1) && (gg <= G);
        const int gc = min(max(gg, 1), G);
        const int j  = 4 * gc;                             // cols j..j+3
        const int i0 = 2 + RS * blockIdx.y;
        const int count = min(RS, (n - 2) - i0);           // even by constr.
        const float*  pj = eps + (j - 2);
        const size_t  sn = (size_t)n;
        const f2 inv2d2  = mk(inv_2d, inv_2d);
        const f2 inv4dd2 = mk(inv_4dd, inv_4dd);

        Row s0, s1, s2, s3, s4, s5, s6, s7;
        load_row(s0, pj + (size_t)(i0 - 2) * sn);
        load_row(s1, pj + (size_t)(i0 - 1) * sn);
        load_row(s2, pj + (size_t)(i0    ) * sn);
        load_row(s3, pj + (size_t)(i0 + 1) * sn);
        load_row(s4, pj + (size_t)(i0 + 2) * sn);
        load_row(s5, pj + (size_t)(i0 + 3) * sn);
        const float* pnext = pj + (size_t)(i0 + 4) * sn;

        f2 acc2 = mk(0.0f, 0.0f);
        // phase: compute output rows (i0+k, i0+k+1) from 6 resident rows,
        // prefetch rows i0+k+4, i0+k+5 (consumed next phase).
        #define PHASEP(ph, A0, A1, A2, A3, A4, A5, L0, L1)                    \
        {                                                                     \
            const int k = kbase + 2 * (ph);                                   \
            if (k < count) {                                                  \
                if (k + 2 < count) {                                          \
                    load_row(L0, pnext);                                      \
                    load_row(L1, pnext + sn);                                 \
                }                                                             \
                pnext += 2 * sn;                                              \
                acc2 = acc2 + compute_pair(A0, A1, A2, A3, A4, A5,            \
                                           inv2d2, inv4dd2);                  \
            }                                                                 \
        }

        #pragma unroll 1
        for (int kbase = 0; kbase < RS; kbase += 8) {
            PHASEP(0, s0, s1, s2, s3, s4, s5, s6, s7)
            PHASEP(1, s2, s3, s4, s5, s6, s7, s0, s1)
            PHASEP(2, s4, s5, s6, s7, s0, s1, s2, s3)
            PHASEP(3, s6, s7, s0, s1, s2, s3, s4, s5)
        }
        #undef PHASEP

        acc = valid ? (acc2.x + acc2.y) : 0.0f;
    } else {
        // ================= frame (edge_order=1 one-sided) path =============
        const float inv_d = inv_2d + inv_2d;
        const int nfr = 4 * n + 8 * (n - 4);
        const int fb  = (int)blockIdx.y - nstrip;                 // 0..FEXTRA-1
        const int tid = (fb * gridDim.x + blockIdx.x) * 256 + threadIdx.x;
        const int nth = FEXTRA * gridDim.x * 256;

        for (int idx = tid; idx < nfr; idx += nth) {
            int i, j;
            if (idx < 4 * n) {
                const int rr = (idx >= n) + (idx >= 2 * n) + (idx >= 3 * n);
                j = idx - rr * n;
                i = (rr < 2) ? rr : (n - 4) + rr;                 // 0,1,n-2,n-1
            } else {
                const int t = idx - 4 * n;
                i = 2 + (t >> 3);                                 // rows 2..n-3
                const int cc = t & 7;
                j = (cc < 4) ? cc : (n - 8) + cc;                 // 0..3, n-4..n-1
            }

            const float ex0 = gex(eps, n, i, j, inv_d, inv_2d);
            const float ey0 = gey(eps, n, i, j, inv_d, inv_2d);

            float exx, exy, eyy;
            if (i == 0)
                exx = (gex(eps, n, 1, j, inv_d, inv_2d) - ex0) * inv_d;
            else if (i == n - 1)
                exx = (ex0 - gex(eps, n, n - 2, j, inv_d, inv_2d)) * inv_d;
            else
                exx = (gex(eps, n, i + 1, j, inv_d, inv_2d)
                     - gex(eps, n, i - 1, j, inv_d, inv_2d)) * inv_2d;

            if (j == 0)
                exy = (gex(eps, n, i, 1, inv_d, inv_2d) - ex0) * inv_d;
            else if (j == n - 1)
                exy = (ex0 - gex(eps, n, i, n - 2, inv_d, inv_2d)) * inv_d;
            else
                exy = (gex(eps, n, i, j + 1, inv_d, inv_2d)
                     - gex(eps, n, i, j - 1, inv_d, inv_2d)) * inv_2d;

            if (j == 0)
                eyy = (gey(eps, n, i, 1, inv_d, inv_2d) - ey0) * inv_d;
            else if (j == n - 1)
                eyy = (ey0 - gey(eps, n, i, n - 2, inv_d, inv_2d)) * inv_d;
            else
                eyy = (gey(eps, n, i, j + 1, inv_d, inv_2d)
                     - gey(eps, n, i, j - 1, inv_d, inv_2d)) * inv_2d;

            const float ev = fmaxf(__builtin_amdgcn_sqrtf(fmaf(ex0, ex0, ey0 * ey0)), EVF);
            const float num = fmaf(ex0 * ex0, eyy,
                              fmaf(-2.0f * ex0 * ey0, exy, ey0 * ey0 * exx));
            const float kabs = fabsf(num) * __builtin_amdgcn_rcpf(ev * ev * ev);

            const float aw = fabsf(eg(eps, n, i, j) + 1e-6f);
            const float mx = fmaxf(ev, aw);
            const float mn = fminf(ev, aw);
            const float t  = mn * __builtin_amdgcn_rcpf(mx);
            const float t2 = t * t;
            float pl = fmaf(t2, -0.01172120f, 0.05265332f);
            pl = fmaf(t2, pl, -0.11643287f);
            pl = fmaf(t2, pl, 0.19354346f);
            pl = fmaf(t2, pl, -0.33262347f);
            pl = fmaf(t2, pl, 0.99997726f);
            pl *= t;
            const float at = (ev > aw) ? (PIH - pl) : pl;

            acc += fmaxf(fmaf(kabs, at, -PID), 0.0f);
        }
    }

    // ---- reduction: wave -> block (LDS) -> one atomic per block ----
    __shared__ float wsum[4];
    #pragma unroll
    for (int off = 32; off; off >>= 1)
        acc += __shfl_down(acc, off, 64);
    if ((threadIdx.x & 63) == 0) wsum[threadIdx.x >> 6] = acc;
    __syncthreads();
    if (threadIdx.x == 0)
        atomicAdd(out, (wsum[0] + wsum[1] + wsum[2] + wsum[3]) * d * d);
}

extern "C" void kernel_launch(void* const* d_in, const int* in_sizes, int n_in,
                              void* d_out, int out_size, void* d_ws, size_t ws_size,
                              hipStream_t stream) {
    const float* eps = (const float*)d_in[0];
    const float* gs  = (const float*)d_in[1];
    float* out = (float*)d_out;

    const long long tot = (long long)in_sizes[0];
    const int n = (int)(sqrt((double)tot) + 0.5);   // 8192

    hipMemsetAsync(out, 0, sizeof(float), stream);

    const int G = (n - 8) / 4;                      // interior col groups
    const int nstrip = (n - 4 + RS - 1) / RS;       // interior rows [2, n-2)

    dim3 block(256, 1);
    dim3 grid(n / 1024, nstrip + FEXTRA);           // last FEXTRA y-rows: frame
    fab_fused<<<grid, block, 0, stream>>>(eps, gs, out, n, G, nstrip);
}